// Round 6
// baseline (35.977 us; speedup 1.0000x reference)
//
#include <hip/hip_runtime.h>
#include <hip/hip_bf16.h>

#define BATCH 64
#define HH 32
#define WW 32
#define CIN 64
#define COUT 64
#define KFEAT 576   // 3*3*64, flattened as ci*9 + kh*3 + kw (ci major)

typedef __bf16 bf16x8 __attribute__((ext_vector_type(8)));
typedef float f32x4 __attribute__((ext_vector_type(4)));

static __device__ __forceinline__ ushort f2bf_bits(float f) {
  __bf16 b = (__bf16)f;
  return __builtin_bit_cast(ushort, b);
}

// One block per output pixel (h,w). 256 threads = 4 waves.
// Per-pixel GEMM: C[64b][64co] = patches[64b][576k] * K[576k][64co], K-permuted
// as k' = p*64 + ci. Phase-aligned pixel order (R5): at step t all blocks read
// the input tile with hp%3==t/3, wp%3==t%3 -> concurrent misses merge in L2.
// ROUND-6 DELTA (vs R5): TRIPLE-buffered LDS -> ONE barrier per step (9 vs 18),
// and the input pipeline is 2 steps deep with a single st reg set: at iter t,
// writebuf(t+1) consumes loads issued at iter t-1 (landed -> zero vmcnt stall),
// then issue(t+2) goes in flight. Weight loads stay JIT (R3: prefetch neutral).
__global__ __launch_bounds__(256, 4) void LocalConv_kernel(
    const float* __restrict__ in, const float* __restrict__ ker,
    const float* __restrict__ bias, float* __restrict__ out) {
  // A buffers: [3][64 rows][64 ci] bf16, row stride 128B, XOR-swizzled by
  // byte ^= ((row&7)<<4) to kill the stride-128B bank conflict (G4).
  __shared__ __align__(16) ushort Ab[3][64 * 64];

  const int orig = blockIdx.x;
  // XCD-aware swizzle (T1): 1024 blocks, 8 XCDs, 128 contiguous per XCD
  // -> each XCD covers 4 consecutive h rows (input slice L2-fits).
  const int hw = (orig & 7) * 128 + (orig >> 3);
  const int h = hw >> 5, w = hw & 31;
  const int hm = h % 3, wm = w % 3;
  const int tid = threadIdx.x;
  const int lane = tid & 63;
  const int wave = tid >> 6;

  const float* kerhw = ker + (size_t)hw * (KFEAT * COUT);

  // Step t -> (hp, wp, p): the unique 3x3-neighbor with hp===t/3, wp===t%3
  // (mod 3). Each block still visits all 9 offsets exactly once.
  auto offs = [&](int t, int& hp, int& wp, int& p) {
    const int t3 = t / 3, t0 = t % 3;
    const int dh = ((t3 + 4 - hm) % 3) - 1;  // (h+dh) % 3 == t3
    const int dw = ((t0 + 4 - wm) % 3) - 1;  // (w+dw) % 3 == t0
    hp = h + dh;
    wp = w + dw;
    p = (dh + 1) * 3 + (dw + 1);
  };

  float4 st[4];  // in-flight staging regs (single set, pipeline depth 2)

  auto issue = [&](int hp, int wp) {
    const bool ok = ((unsigned)hp < (unsigned)HH) && ((unsigned)wp < (unsigned)WW);
    const float* src = in + ((size_t)hp * WW + wp) * CIN;
#pragma unroll
    for (int i = 0; i < 4; ++i) {
      const int c = i * 256 + tid;       // 0..1023 chunks of float4
      const int brow = c >> 4;           // batch row 0..63
      const int c16 = c & 15;            // float4 index within row
      if (ok) {
        st[i] = *reinterpret_cast<const float4*>(
            src + (size_t)brow * (HH * WW * CIN) + c16 * 4);
      } else {
        st[i] = make_float4(0.f, 0.f, 0.f, 0.f);  // SAME zero padding
      }
    }
  };

  auto issue_step = [&](int t) {
    int hp, wp, pu;
    offs(t, hp, wp, pu);
    issue(hp, wp);
  };

  auto writebuf = [&](int buf_idx) {
    ushort* buf = &Ab[buf_idx][0];
#pragma unroll
    for (int i = 0; i < 4; ++i) {
      const int c = i * 256 + tid;
      const int brow = c >> 4, c16 = c & 15;
      union { ushort us[4]; uint2 u2; } pk;
      pk.us[0] = f2bf_bits(st[i].x);
      pk.us[1] = f2bf_bits(st[i].y);
      pk.us[2] = f2bf_bits(st[i].z);
      pk.us[3] = f2bf_bits(st[i].w);
      const int byteofs = brow * 128 + ((c16 * 8) ^ ((brow & 7) << 4));
      *reinterpret_cast<uint2*>(reinterpret_cast<char*>(buf) + byteofs) = pk.u2;
    }
  };

  f32x4 acc[4];
#pragma unroll
  for (int m = 0; m < 4; ++m) acc[m] = (f32x4){0.f, 0.f, 0.f, 0.f};

  const int co = wave * 16 + (lane & 15);  // this wave's co slice
  const int kgrp = lane >> 4;              // 0..3, k-group within frag

  // Prologue: tile 0 -> LDS; tile 1 loads in flight; Ab[0] visible.
  issue_step(0);
  writebuf(0);
  issue_step(1);
  __syncthreads();

  for (int t = 0; t < 9; ++t) {
    if (t < 8) writebuf((t + 1) % 3);  // st = tile t+1 (landed an iter ago)
    if (t < 7) issue_step(t + 2);      // st = tile t+2, in flight

    int hh_, ww_, pcur;
    offs(t, hh_, ww_, pcur);  // weight pixel index for this step

    const ushort* buf = &Ab[t % 3][0];
    // kernel element (ci,co) for pixel pcur: kerhw[ci*576 + pcur*64 + co]
    const float* kp = kerhw + pcur * COUT + co;
#pragma unroll
    for (int ks = 0; ks < 2; ++ks) {  // two K=32 steps per pixel
      const int ci0 = ks * 32 + kgrp * 8;
      bf16x8 bfrag;
#pragma unroll
      for (int j = 0; j < 8; ++j)
        bfrag[j] = (__bf16)kp[(size_t)(ci0 + j) * KFEAT];
#pragma unroll
      for (int m = 0; m < 4; ++m) {
        const int row = m * 16 + (lane & 15);
        const int byteofs =
            row * 128 + ((ks * 64 + kgrp * 16) ^ ((row & 7) << 4));
        bf16x8 afrag = *reinterpret_cast<const bf16x8*>(
            reinterpret_cast<const char*>(buf) + byteofs);
        acc[m] = __builtin_amdgcn_mfma_f32_16x16x32_bf16(afrag, bfrag, acc[m],
                                                         0, 0, 0);
      }
    }

    // ONE barrier per step: writebuf(t+1) touched Ab[(t+1)%3], whose last
    // readers (compute t-2) finished two barriers ago; compute(t+1) reads it
    // only after this barrier.
    if (t < 8) __syncthreads();
  }

  // Epilogue: C/D layout (16x16x32): col = lane&15, row = (lane>>4)*4 + reg.
  const float bv = bias[hw * COUT + co];
#pragma unroll
  for (int m = 0; m < 4; ++m) {
#pragma unroll
    for (int r = 0; r < 4; ++r) {
      const int b = m * 16 + kgrp * 4 + r;
      out[((size_t)b * (HH * WW) + hw) * COUT + co] = acc[m][r] + bv;
    }
  }
}

extern "C" void kernel_launch(void* const* d_in, const int* in_sizes, int n_in,
                              void* d_out, int out_size, void* d_ws,
                              size_t ws_size, hipStream_t stream) {
  const float* in = (const float*)d_in[0];
  const float* ker = (const float*)d_in[1];
  const float* bias = (const float*)d_in[2];
  float* out = (float*)d_out;
  (void)in_sizes; (void)n_in; (void)out_size; (void)d_ws; (void)ws_size;
  LocalConv_kernel<<<dim3(HH * WW), dim3(256), 0, stream>>>(in, ker, bias, out);
}